// Round 21
// baseline (134.836 us; speedup 1.0000x reference)
//
#include <hip/hip_runtime.h>
#include <hip/hip_bf16.h>
#include <stdint.h>

#define NN 4096
#define NBLK 3920                  // sum_{d=0}^{63} (64-d)*ceil((d+1)/16)

typedef __attribute__((ext_vector_type(8))) __bf16 bf16x8;
typedef __attribute__((ext_vector_type(8))) short  s16x8;
typedef __attribute__((ext_vector_type(4))) float  f32x4;

__device__ __forceinline__ ushort f2bf(float f) {
    uint32_t u = __builtin_bit_cast(uint32_t, f);
    u += 0x7fffu + ((u >> 16) & 1u);            // RNE to bf16
    return (ushort)(u >> 16);
}

// ---------- fused prep: z=0 conv A (triu, bf16), z=1 conv B^T (triu, bf16), z=2 zero C 64-subtiles ----------
__global__ __launch_bounds__(256) void prep(const float* __restrict__ A,
                                            const float* __restrict__ B,
                                            ushort* __restrict__ Au,
                                            ushort* __restrict__ BTu,
                                            float* __restrict__ C) {
    const int role = blockIdx.z;
    const int tr = blockIdx.y;
    const int tc = blockIdx.x;
    const int tid = threadIdx.x;

    if (role == 0) {
        if (tc < tr) return;                     // lower A-tiles never read
        const bool diag = (tc == tr);
#pragma unroll
        for (int q = 0; q < 8; ++q) {
            int g = q * 256 + tid;
            int r = g >> 4, c0 = (g & 15) << 3;
            int row = tr * 128 + r, col0 = tc * 128 + c0;
            const float* p = A + (size_t)row * NN + col0;
            f32x4 a0 = *reinterpret_cast<const f32x4*>(p);
            f32x4 a1 = *reinterpret_cast<const f32x4*>(p + 4);
            s16x8 o;
#pragma unroll
            for (int j = 0; j < 8; ++j) {
                float f = (j < 4) ? a0[j] : a1[j - 4];
                if (diag && (col0 + j) < row) f = 0.0f;
                o[j] = (short)f2bf(f);
            }
            *reinterpret_cast<s16x8*>(Au + (size_t)row * NN + col0) = o;
        }
        return;
    }

    if (role == 1) {
        // BTu[j][k] = (j >= k) ? bf16(B[k][j]) : 0 ; tr = k-tile, tc = j-tile
        if (tc < tr) return;
        const bool diag = (tc == tr);
        __shared__ ushort tile[128][129];        // pad 129: transpose read 2-way (free)
#pragma unroll
        for (int q = 0; q < 16; ++q) {
            int g = q * 256 + tid;
            int r = g >> 5, f4 = g & 31;
            int krow = tr * 128 + r;
            const float* p = B + (size_t)krow * NN + tc * 128 + f4 * 4;
            f32x4 v = *reinterpret_cast<const f32x4*>(p);
#pragma unroll
            for (int j = 0; j < 4; ++j) {
                int col = f4 * 4 + j;
                float f = v[j];
                if (diag && (tc * 128 + col) < krow) f = 0.0f;
                tile[r][col] = f2bf(f);
            }
        }
        __syncthreads();
#pragma unroll
        for (int q = 0; q < 8; ++q) {
            int g = q * 256 + tid;
            int orow = g >> 4, ch = g & 15;
            s16x8 o;
#pragma unroll
            for (int j = 0; j < 8; ++j) o[j] = (short)tile[ch * 8 + j][orow];
            *reinterpret_cast<s16x8*>(BTu + (size_t)(tc * 128 + orow) * NN + tr * 128 + ch * 8) = o;
        }
        return;
    }

    // role 2: per 64-subtile of this 128-tile, zero if lower (i64>j64) or multi-chunk (d64>=16)
    {
#pragma unroll
        for (int qi = 0; qi < 2; ++qi)
#pragma unroll
            for (int qj = 0; qj < 2; ++qj) {
                int i64 = 2 * tr + qi, j64 = 2 * tc + qj;
                if (!((i64 > j64) || ((j64 - i64) >= 16))) continue;
                f32x4 z = {0.f, 0.f, 0.f, 0.f};
#pragma unroll
                for (int v = 0; v < 4; ++v) {
                    int r = (tid >> 4) + v * 16;
                    int c4 = (tid & 15) * 4;
                    *reinterpret_cast<f32x4*>(
                        C + (size_t)(tr * 128 + qi * 64 + r) * NN + tc * 128 + qj * 64 + c4) = z;
                }
            }
    }
}

// ---------------- barrier-free 1-wave MFMA kernel: 64x64 tile, BK=32, self-paced pipeline ----------------
// r21: seven structural nulls show barrier-coupled waves pay ~5600cy/step regardless of conflicts/
// locality/barriers/tile-size. A 64-thread block needs NO barriers: gload_lds -> counted vmcnt ->
// ds_read -> MFMA all wave-internal. 10 blocks/CU = 10 independent self-paced streams. Overwrite
// race (2-buf) prevented by draining ds_reads (lgkmcnt(0)) before STAGE(t+2) overwrites buf[cur].
// XOR swizzle kept (r16). Jobs: 64-grid, cap 16 k-tiles, d-descending LPT.
__global__ __launch_bounds__(64) void trimm_wave(const ushort* __restrict__ Au,
                                                 const ushort* __restrict__ BTu,
                                                 float* __restrict__ C) {
    const int lane = threadIdx.x;

    // ---- decode id -> (bi, bj, chunk c of nc), d descending ----
    int id = blockIdx.x;
    int d, nc = 1, bi = 0, c = 0;
    for (d = 63; d >= 0; --d) {
        nc = (d + 16) >> 4;                      // ceil((d+1)/16)
        int cnt = (64 - d) * nc;
        if (id < cnt) { bi = id / nc; c = id % nc; break; }
        id -= cnt;
    }
    const int bj = bi + d;
    const int L = d + 1;                         // k-tiles of 64 in [bi, bj]
    const int kt0 = (c * L) / nc, kt1 = ((c + 1) * L) / nc;
    const int k_base = (bi + kt0) * 64;
    const int nsteps = (kt1 - kt0) * 2;          // BK=32 steps (2..32)

    __shared__ ushort lA[2][64 * 32];            // 2 x 4 KB
    __shared__ ushort lB[2][64 * 32];            // 2 x 4 KB (16 KB total -> 10 blocks/CU)

    const int l16 = lane & 15, kh = lane >> 4;

    // staging: 256 chunks/operand/stage; lane does chunks g = q*64+lane, q=0..3, per operand.
    // chunk g -> linear LDS 16B-slot g; source kslot = (g&3)^((g>>3)&3)  [XOR swizzle, r16]
    const int gq0 = 0 * 64 + lane, gq1 = 1 * 64 + lane, gq2 = 2 * 64 + lane, gq3 = 3 * 64 + lane;
#define KS(g) ((((g) & 3) ^ (((g) >> 3) & 3)) << 3)
    const ushort* pA0 = Au  + (size_t)(bi * 64 + (gq0 >> 2)) * NN + KS(gq0) + k_base;
    const ushort* pA1 = Au  + (size_t)(bi * 64 + (gq1 >> 2)) * NN + KS(gq1) + k_base;
    const ushort* pA2 = Au  + (size_t)(bi * 64 + (gq2 >> 2)) * NN + KS(gq2) + k_base;
    const ushort* pA3 = Au  + (size_t)(bi * 64 + (gq3 >> 2)) * NN + KS(gq3) + k_base;
    const ushort* pB0 = BTu + (size_t)(bj * 64 + (gq0 >> 2)) * NN + KS(gq0) + k_base;
    const ushort* pB1 = BTu + (size_t)(bj * 64 + (gq1 >> 2)) * NN + KS(gq1) + k_base;
    const ushort* pB2 = BTu + (size_t)(bj * 64 + (gq2 >> 2)) * NN + KS(gq2) + k_base;
    const ushort* pB3 = BTu + (size_t)(bj * 64 + (gq3 >> 2)) * NN + KS(gq3) + k_base;
#undef KS
    const int lo0 = gq0 * 8, lo1 = gq1 * 8, lo2 = gq2 * 8, lo3 = gq3 * 8;

#define GLOAD(src, dst) __builtin_amdgcn_global_load_lds(                      \
        (const __attribute__((address_space(1))) void*)(src),                  \
        (__attribute__((address_space(3))) void*)(dst), 16, 0, 0)
#define STAGE(buf, off)                                                        \
    do {                                                                       \
        GLOAD(pA0 + (off), &lA[buf][lo0]); GLOAD(pA1 + (off), &lA[buf][lo1]);  \
        GLOAD(pA2 + (off), &lA[buf][lo2]); GLOAD(pA3 + (off), &lA[buf][lo3]);  \
        GLOAD(pB0 + (off), &lB[buf][lo0]); GLOAD(pB1 + (off), &lB[buf][lo1]);  \
        GLOAD(pB2 + (off), &lB[buf][lo2]); GLOAD(pB3 + (off), &lB[buf][lo3]);  \
    } while (0)

    f32x4 zerov = {0.f, 0.f, 0.f, 0.f};
    f32x4 acc[4][4];
#pragma unroll
    for (int m = 0; m < 4; ++m)
#pragma unroll
        for (int n = 0; n < 4; ++n) acc[m][n] = zerov;

    // prologue: 2 stages in flight (8 loads each)
    STAGE(0, 0);
    if (nsteps > 1) STAGE(1, 32);

    for (int t = 0; t < nsteps; ++t) {
        const int cur = t & 1;
        // counted vmcnt: stage t done; stage t+1's 8 loads stay outstanding (never 0 in-loop)
        if (t + 1 < nsteps) asm volatile("s_waitcnt vmcnt(8)" ::: "memory");
        else                asm volatile("s_waitcnt vmcnt(0)" ::: "memory");
        __builtin_amdgcn_sched_barrier(0);

        bf16x8 af[4], bfr[4];
#pragma unroll
        for (int m = 0; m < 4; ++m) {
            int row = m * 16 + l16;
            af[m] = *reinterpret_cast<const bf16x8*>(&lA[cur][row * 32 + ((kh ^ ((row >> 1) & 3)) << 3)]);
            bfr[m] = *reinterpret_cast<const bf16x8*>(&lB[cur][row * 32 + ((kh ^ ((row >> 1) & 3)) << 3)]);
        }
        // drain ds_reads before overwriting buf[cur] with stage t+2 (2-buffer reuse)
        asm volatile("s_waitcnt lgkmcnt(0)" ::: "memory");
        __builtin_amdgcn_sched_barrier(0);
        if (t + 2 < nsteps) STAGE(cur, (t + 2) * 32);
        __builtin_amdgcn_sched_barrier(0);

#pragma unroll
        for (int m = 0; m < 4; ++m)
#pragma unroll
            for (int n = 0; n < 4; ++n)
                acc[m][n] = __builtin_amdgcn_mfma_f32_16x16x32_bf16(af[m], bfr[n], acc[m][n], 0, 0, 0);
    }
#undef STAGE
#undef GLOAD

    // C/D layout: col = lane&15, row = (lane>>4)*4 + reg
    const int rowb = bi * 64 + kh * 4;
    const int colb = bj * 64 + l16;
    if (nc == 1) {
#pragma unroll
        for (int m = 0; m < 4; ++m)
#pragma unroll
            for (int n = 0; n < 4; ++n)
#pragma unroll
                for (int r = 0; r < 4; ++r)
                    C[(size_t)(rowb + m * 16 + r) * NN + colb + n * 16] = acc[m][n][r];
    } else {
#pragma unroll
        for (int m = 0; m < 4; ++m)
#pragma unroll
            for (int n = 0; n < 4; ++n)
#pragma unroll
                for (int r = 0; r < 4; ++r)
                    unsafeAtomicAdd(&C[(size_t)(rowb + m * 16 + r) * NN + colb + n * 16], acc[m][n][r]);
    }
}

// ---------------- fp32 fallback (only if ws too small) ----------------
__global__ __launch_bounds__(256) void tri_fp32(const float* __restrict__ A,
                                                const float* __restrict__ B,
                                                float* __restrict__ C) {
    const int bi = blockIdx.y, bj = blockIdx.x, tid = threadIdx.x;
    const int r0 = (tid >> 4) << 2, c0 = (tid & 15) << 2;
    f32x4 z = {0.f, 0.f, 0.f, 0.f};
    if (bi > bj) {
#pragma unroll
        for (int r = 0; r < 4; ++r)
            *reinterpret_cast<f32x4*>(C + (size_t)(bi * 64 + r0 + r) * NN + bj * 64 + c0) = z;
        return;
    }
    __shared__ float As[64][65], Bs[64][65];
    float acc[4][4] = {};
    for (int kt = bi; kt <= bj; ++kt) {
        const int k0 = kt * 64;
#pragma unroll
        for (int q = 0; q < 4; ++q) {
            int g = q * 256 + tid, r = g >> 4, f4 = g & 15;
            f32x4 va = *reinterpret_cast<const f32x4*>(A + (size_t)(bi * 64 + r) * NN + k0 + f4 * 4);
            f32x4 vb = *reinterpret_cast<const f32x4*>(B + (size_t)(k0 + r) * NN + bj * 64 + f4 * 4);
#pragma unroll
            for (int j = 0; j < 4; ++j) {
                As[r][f4 * 4 + j] = (k0 + f4 * 4 + j >= bi * 64 + r) ? va[j] : 0.f;
                Bs[r][f4 * 4 + j] = (bj * 64 + f4 * 4 + j >= k0 + r) ? vb[j] : 0.f;
            }
        }
        __syncthreads();
        for (int kk = 0; kk < 64; ++kk) {
#pragma unroll
            for (int r = 0; r < 4; ++r) {
                float a = As[r0 + r][kk];
#pragma unroll
                for (int cc = 0; cc < 4; ++cc) acc[r][cc] += a * Bs[kk][c0 + cc];
            }
        }
        __syncthreads();
    }
#pragma unroll
    for (int r = 0; r < 4; ++r) {
        f32x4 o = {acc[r][0], acc[r][1], acc[r][2], acc[r][3]};
        *reinterpret_cast<f32x4*>(C + (size_t)(bi * 64 + r0 + r) * NN + bj * 64 + c0) = o;
    }
}

extern "C" void kernel_launch(void* const* d_in, const int* in_sizes, int n_in,
                              void* d_out, int out_size, void* d_ws, size_t ws_size,
                              hipStream_t stream) {
    const float* A = (const float*)d_in[0];
    const float* B = (const float*)d_in[1];
    float* C = (float*)d_out;

    const size_t need = (size_t)2 * NN * NN * sizeof(ushort);   // 64 MB
    if (ws_size >= need) {
        ushort* Au  = (ushort*)d_ws;
        ushort* BTu = Au + (size_t)NN * NN;
        prep<<<dim3(32, 32, 3), 256, 0, stream>>>(A, B, Au, BTu, C);
        trimm_wave<<<NBLK, 64, 0, stream>>>(Au, BTu, C);
    } else {
        tri_fp32<<<dim3(64, 64), 256, 0, stream>>>(A, B, C);
    }
}

// Round 22
// 118.812 us; speedup vs baseline: 1.1349x; 1.1349x over previous
//
#include <hip/hip_runtime.h>
#include <hip/hip_bf16.h>
#include <stdint.h>

#define NN 4096
#define NBLK 260                   // sum_{d=0}^{15} (16-d)*ceil((d+1)/4)  (256-tile jobs)
#define NITEMS16 1000              // r16 fallback: 128-tile jobs, cap 8
#define SLOTS_PER_XCD 132
#define GRID16 (8 * SLOTS_PER_XCD)

typedef __attribute__((ext_vector_type(8))) __bf16 bf16x8;
typedef __attribute__((ext_vector_type(8))) short  s16x8;
typedef __attribute__((ext_vector_type(4))) float  f32x4;

__device__ __forceinline__ ushort f2bf(float f) {
    uint32_t u = __builtin_bit_cast(uint32_t, f);
    u += 0x7fffu + ((u >> 16) & 1u);            // RNE to bf16
    return (ushort)(u >> 16);
}

__device__ __forceinline__ int col_jobs8(int bj) { // r16 fallback decode helper (cap 8)
    int L = bj + 1, a = L >> 3, b = L & 7;
    return 4 * a * (a + 1) + b * (a + 1);
}

// ---------- fused prep (r20 verbatim): conv A, conv B^T, zero C tiles ----------
__global__ __launch_bounds__(256) void prep(const float* __restrict__ A,
                                            const float* __restrict__ B,
                                            ushort* __restrict__ Au,
                                            ushort* __restrict__ BTu,
                                            float* __restrict__ C) {
    const int role = blockIdx.z;
    const int tr = blockIdx.y;
    const int tc = blockIdx.x;
    const int tid = threadIdx.x;

    if (role == 0) {
        if (tc < tr) return;
        const bool diag = (tc == tr);
#pragma unroll
        for (int q = 0; q < 8; ++q) {
            int g = q * 256 + tid;
            int r = g >> 4, c0 = (g & 15) << 3;
            int row = tr * 128 + r, col0 = tc * 128 + c0;
            const float* p = A + (size_t)row * NN + col0;
            f32x4 a0 = *reinterpret_cast<const f32x4*>(p);
            f32x4 a1 = *reinterpret_cast<const f32x4*>(p + 4);
            s16x8 o;
#pragma unroll
            for (int j = 0; j < 8; ++j) {
                float f = (j < 4) ? a0[j] : a1[j - 4];
                if (diag && (col0 + j) < row) f = 0.0f;
                o[j] = (short)f2bf(f);
            }
            *reinterpret_cast<s16x8*>(Au + (size_t)row * NN + col0) = o;
        }
        return;
    }

    if (role == 1) {
        if (tc < tr) return;
        const bool diag = (tc == tr);
        __shared__ ushort tile[128][129];
#pragma unroll
        for (int q = 0; q < 16; ++q) {
            int g = q * 256 + tid;
            int r = g >> 5, f4 = g & 31;
            int krow = tr * 128 + r;
            const float* p = B + (size_t)krow * NN + tc * 128 + f4 * 4;
            f32x4 v = *reinterpret_cast<const f32x4*>(p);
#pragma unroll
            for (int j = 0; j < 4; ++j) {
                int col = f4 * 4 + j;
                float f = v[j];
                if (diag && (tc * 128 + col) < krow) f = 0.0f;
                tile[r][col] = f2bf(f);
            }
        }
        __syncthreads();
#pragma unroll
        for (int q = 0; q < 8; ++q) {
            int g = q * 256 + tid;
            int orow = g >> 4, ch = g & 15;
            s16x8 o;
#pragma unroll
            for (int j = 0; j < 8; ++j) o[j] = (short)tile[ch * 8 + j][orow];
            *reinterpret_cast<s16x8*>(BTu + (size_t)(tc * 128 + orow) * NN + tr * 128 + ch * 8) = o;
        }
        return;
    }

    // zero if lower 256-tile OR upper 256-tile with d256 >= 4 (covers both main & fallback atomics)
    {
        int I = tr >> 1, J = tc >> 1;
        bool need = (I > J) || ((J - I) >= 4);
        if (!need) return;
        int r = tid >> 1, cb = (tid & 1) * 64;
        float* p = C + (size_t)(tr * 128 + r) * NN + tc * 128 + cb;
        f32x4 z = {0.f, 0.f, 0.f, 0.f};
#pragma unroll
        for (int v = 0; v < 16; ++v) *reinterpret_cast<f32x4*>(p + v * 4) = z;
    }
}

// ---------------- MAIN: 256² tile, 4-deep pipeline, counted vmcnt(8), 1 barrier/K-step ----------------
// Tile t in buf[t&3] (4 x 32KB = 128KB dynamic LDS). Prologue stages t=0,1,2. During t's 2 phases
// we stage t+3 into buf[(t-1)&3] (safe: barrier(t) retired t-1's reads). Top-of-t wait covers only
// t's own loads -> vmcnt(8) steady (t+1,t+2 in flight), 4/0 in epilogue — never a full drain
// in-loop (T4). Phase: {stage A|B of t+3, ds_read quadrant, setprio(1), 16 MFMA, setprio(0)} (T3/T5).
// Reads use r16's verified XOR swizzle (conflict-free, coalesced source). Decode/C-write = r20.
__global__ __launch_bounds__(512, 1) void trimm_8ph(const ushort* __restrict__ Au,
                                                    const ushort* __restrict__ BTu,
                                                    float* __restrict__ C) {
    extern __shared__ ushort lds[];              // 4 buffers x 16384 ushorts (A at +0, B at +8192)
    const int tid = threadIdx.x;

    // decode id -> (I, J, chunk c of nch), d descending (r20 verbatim)
    int id = blockIdx.x;
    int dd, nch = 1, I = 0, c = 0;
    for (dd = 15; dd >= 0; --dd) {
        int nc = (dd + 4) >> 2;
        int cnt = (16 - dd) * nc;
        if (id < cnt) { I = id / nc; c = id % nc; nch = nc; break; }
        id -= cnt;
    }
    const int J = I + dd;
    const int L = dd + 1;
    const int kt0 = (c * L) / nch, kt1 = ((c + 1) * L) / nch;
    const int k_base = (I + kt0) * 256;
    const int nkt = (kt1 - kt0) * 8;             // BK=32 K-steps (8..32)

    const int wid = tid >> 6, lane = tid & 63;
    const int wr = wid >> 2, wc = wid & 3;       // wave out = 128x64
    const int l16 = lane & 15, kh = lane >> 4;

    // staging: per tile, per thread: 2 A-chunks (g, 512+g) + 2 B-chunks. chunk g -> row=g>>2,
    // source kslot = (g&3)^((g>>3)&3) (XOR swizzle, r16); LDS dest linear at g*8 ushorts.
    const int g0 = tid, g1 = 512 + tid;
    const int ks0 = ((g0 & 3) ^ ((g0 >> 3) & 3)) << 3;
    const int ks1 = ((g1 & 3) ^ ((g1 >> 3) & 3)) << 3;
    const ushort* pA0 = Au  + (size_t)(I * 256 + (g0 >> 2)) * NN + ks0 + k_base;
    const ushort* pA1 = Au  + (size_t)(I * 256 + (g1 >> 2)) * NN + ks1 + k_base;
    const ushort* pB0 = BTu + (size_t)(J * 256 + (g0 >> 2)) * NN + ks0 + k_base;
    const ushort* pB1 = BTu + (size_t)(J * 256 + (g1 >> 2)) * NN + ks1 + k_base;
    const int loA0 = g0 * 8, loA1 = g1 * 8;
    const int loB0 = 8192 + g0 * 8, loB1 = 8192 + g1 * 8;

#define GLOAD(src, dst) __builtin_amdgcn_global_load_lds(                      \
        (const __attribute__((address_space(1))) void*)(src),                  \
        (__attribute__((address_space(3))) void*)(dst), 16, 0, 0)
#define STAGE_A(b, t) do { int _o = (t) * 32; ushort* _p = &lds[(b) * 16384];  \
        GLOAD(pA0 + _o, _p + loA0); GLOAD(pA1 + _o, _p + loA1); } while (0)
#define STAGE_B(b, t) do { int _o = (t) * 32; ushort* _p = &lds[(b) * 16384];  \
        GLOAD(pB0 + _o, _p + loB0); GLOAD(pB1 + _o, _p + loB1); } while (0)

    f32x4 zerov = {0.f, 0.f, 0.f, 0.f};
    f32x4 acc[8][4];
#pragma unroll
    for (int m = 0; m < 8; ++m)
#pragma unroll
        for (int n = 0; n < 4; ++n) acc[m][n] = zerov;

    // prologue: 3 tiles in flight (12 gloads/wave)
    STAGE_A(0, 0); STAGE_B(0, 0);
    STAGE_A(1, 1); STAGE_B(1, 1);
    STAGE_A(2, 2); STAGE_B(2, 2);

    for (int t = 0; t < nkt; ++t) {
        const int cur = t & 3;
        const int rem = nkt - 1 - t;
        // counted wait: only tile t's 4 loads must land; t+1,t+2 stay outstanding
        if (rem >= 2)      asm volatile("s_waitcnt vmcnt(8)" ::: "memory");
        else if (rem == 1) asm volatile("s_waitcnt vmcnt(4)" ::: "memory");
        else               asm volatile("s_waitcnt vmcnt(0)" ::: "memory");
        __builtin_amdgcn_s_barrier();            // all waves see tile t; t-1 reads retired
        __builtin_amdgcn_sched_barrier(0);

        const ushort* Ab = &lds[cur * 16384];
        const ushort* Bb = Ab + 8192;
        const bool more = (t + 3 < nkt);
        const int nb = (t + 3) & 3;

        // ---- phase 0: stage A(t+3) || read bf[4] + af(mhalf0) || MFMA quadrant 0 ----
        if (more) STAGE_A(nb, t + 3);
        bf16x8 bfr[4], af[4];
#pragma unroll
        for (int j = 0; j < 4; ++j) {
            int rB = wc * 64 + j * 16 + l16;
            bfr[j] = *reinterpret_cast<const bf16x8*>(&Bb[rB * 32 + ((kh ^ ((rB >> 1) & 3)) << 3)]);
        }
#pragma unroll
        for (int i = 0; i < 4; ++i) {
            int rA = wr * 128 + i * 16 + l16;
            af[i] = *reinterpret_cast<const bf16x8*>(&Ab[rA * 32 + ((kh ^ ((rA >> 1) & 3)) << 3)]);
        }
        __builtin_amdgcn_s_setprio(1);
#pragma unroll
        for (int i = 0; i < 4; ++i)
#pragma unroll
            for (int j = 0; j < 4; ++j)
                acc[i][j] = __builtin_amdgcn_mfma_f32_16x16x32_bf16(af[i], bfr[j], acc[i][j], 0, 0, 0);
        __builtin_amdgcn_s_setprio(0);

        // ---- phase 1: stage B(t+3) || read af(mhalf1) || MFMA quadrant 1 ----
        if (more) STAGE_B(nb, t + 3);
#pragma unroll
        for (int i = 0; i < 4; ++i) {
            int rA = wr * 128 + 64 + i * 16 + l16;
            af[i] = *reinterpret_cast<const bf16x8*>(&Ab[rA * 32 + ((kh ^ ((rA >> 1) & 3)) << 3)]);
        }
        __builtin_amdgcn_s_setprio(1);
#pragma unroll
        for (int i = 0; i < 4; ++i)
#pragma unroll
            for (int j = 0; j < 4; ++j)
                acc[4 + i][j] = __builtin_amdgcn_mfma_f32_16x16x32_bf16(af[i], bfr[j], acc[4 + i][j], 0, 0, 0);
        __builtin_amdgcn_s_setprio(0);
    }
#undef STAGE_A
#undef STAGE_B
#undef GLOAD

    // C write (r20 verbatim): col = lane&15, row = (lane>>4)*4 + reg
    const int rowb = I * 256 + wr * 128 + kh * 4;
    const int colb = J * 256 + wc * 64 + l16;
    if (nch == 1) {
#pragma unroll
        for (int m = 0; m < 8; ++m)
#pragma unroll
            for (int n = 0; n < 4; ++n)
#pragma unroll
                for (int r = 0; r < 4; ++r)
                    C[(size_t)(rowb + m * 16 + r) * NN + colb + n * 16] = acc[m][n][r];
    } else {
#pragma unroll
        for (int m = 0; m < 8; ++m)
#pragma unroll
            for (int n = 0; n < 4; ++n)
#pragma unroll
                for (int r = 0; r < 4; ++r)
                    unsafeAtomicAdd(&C[(size_t)(rowb + m * 16 + r) * NN + colb + n * 16], acc[m][n][r]);
    }
}

// ---------------- FALLBACK (r16 verbatim): 128² 2-buf counted-vmcnt, used if LDS attr fails ----------------
__global__ __launch_bounds__(256) void trimm_split(const ushort* __restrict__ Au,
                                                   const ushort* __restrict__ BTu,
                                                   float* __restrict__ C) {
    const int tid = threadIdx.x;
    const int xcd = blockIdx.x & 7;
    int slot = blockIdx.x >> 3;
    const int cols[4] = {31 - xcd, 16 + xcd, 15 - xcd, xcd};
    int bj = -1;
    for (int ci = 0; ci < 4; ++ci) {
        int cj = cols[ci], n = col_jobs8(cj);
        if (slot < n) { bj = cj; break; }
        slot -= n;
    }
    if (bj < 0) return;
    int bi = 0, c = 0, nch = 1;
    for (int i = 0; i <= bj; ++i) {
        int nc = (bj - i + 8) >> 3;
        if (slot < nc) { bi = i; c = slot; nch = nc; break; }
        slot -= nc;
    }
    const int d = bj - bi;
    const int L = d + 1;
    const int kt0 = (c * L) / nch, kt1 = ((c + 1) * L) / nch;
    const int k_base = (bi + kt0) * 128;
    const int nsteps = (kt1 - kt0) * 4;

    __shared__ ushort lA[2][128 * 32];
    __shared__ ushort lB[2][128 * 32];

    const int wid = tid >> 6, lane = tid & 63;
    const int wr = wid >> 1, wc = wid & 1;
    const int l16 = lane & 15, kh = lane >> 4;

    const int g0 = (wid * 2 + 0) * 64 + lane;
    const int g1 = (wid * 2 + 1) * 64 + lane;
    const int ks0 = ((g0 & 3) ^ ((g0 >> 3) & 3)) << 3;
    const int ks1 = ((g1 & 3) ^ ((g1 >> 3) & 3)) << 3;
    const ushort* gaB0 = Au  + (size_t)(bi * 128 + (g0 >> 2)) * NN + ks0 + k_base;
    const ushort* gaB1 = Au  + (size_t)(bi * 128 + (g1 >> 2)) * NN + ks1 + k_base;
    const ushort* gbB0 = BTu + (size_t)(bj * 128 + (g0 >> 2)) * NN + ks0 + k_base;
    const ushort* gbB1 = BTu + (size_t)(bj * 128 + (g1 >> 2)) * NN + ks1 + k_base;
    const int lo0 = (wid * 2 + 0) * 512;
    const int lo1 = (wid * 2 + 1) * 512;

#define STAGE(buf, off)                                                                            \
    do {                                                                                           \
        __builtin_amdgcn_global_load_lds((const __attribute__((address_space(1))) void*)(gaB0 + (off)), \
                                         (__attribute__((address_space(3))) void*)(&lA[buf][lo0]), 16, 0, 0); \
        __builtin_amdgcn_global_load_lds((const __attribute__((address_space(1))) void*)(gaB1 + (off)), \
                                         (__attribute__((address_space(3))) void*)(&lA[buf][lo1]), 16, 0, 0); \
        __builtin_amdgcn_global_load_lds((const __attribute__((address_space(1))) void*)(gbB0 + (off)), \
                                         (__attribute__((address_space(3))) void*)(&lB[buf][lo0]), 16, 0, 0); \
        __builtin_amdgcn_global_load_lds((const __attribute__((address_space(1))) void*)(gbB1 + (off)), \
                                         (__attribute__((address_space(3))) void*)(&lB[buf][lo1]), 16, 0, 0); \
    } while (0)

    f32x4 zero = {0.f, 0.f, 0.f, 0.f};
    f32x4 acc[4][4];
#pragma unroll
    for (int m = 0; m < 4; ++m)
#pragma unroll
        for (int n = 0; n < 4; ++n) acc[m][n] = zero;

    STAGE(0, 0);
    if (nsteps > 1) STAGE(1, 32);

    for (int t = 0; t < nsteps; ++t) {
        const int cur = t & 1;
        if (t + 1 < nsteps) asm volatile("s_waitcnt vmcnt(4)" ::: "memory");
        else                asm volatile("s_waitcnt vmcnt(0)" ::: "memory");
        __builtin_amdgcn_s_barrier();
        __builtin_amdgcn_sched_barrier(0);

        bf16x8 af[4], bfr[4];
#pragma unroll
        for (int m = 0; m < 4; ++m) {
            int row = wr * 64 + m * 16 + l16;
            af[m] = *reinterpret_cast<const bf16x8*>(&lA[cur][row * 32 + ((kh ^ ((row >> 1) & 3)) << 3)]);
        }
#pragma unroll
        for (int n = 0; n < 4; ++n) {
            int row = wc * 64 + n * 16 + l16;
            bfr[n] = *reinterpret_cast<const bf16x8*>(&lB[cur][row * 32 + ((kh ^ ((row >> 1) & 3)) << 3)]);
        }
#pragma unroll
        for (int m = 0; m < 4; ++m)
#pragma unroll
            for (int n = 0; n < 4; ++n)
                acc[m][n] = __builtin_amdgcn_mfma_f32_16x16x32_bf16(af[m], bfr[n], acc[m][n], 0, 0, 0);

        __builtin_amdgcn_s_barrier();
        __builtin_amdgcn_sched_barrier(0);
        if (t + 2 < nsteps) STAGE(cur, (t + 2) * 32);
    }
#undef STAGE

    if (nch == 1) {
#pragma unroll
        for (int m = 0; m < 4; ++m)
#pragma unroll
            for (int n = 0; n < 4; ++n) {
                int row = bi * 128 + wr * 64 + m * 16 + kh * 4;
                int col = bj * 128 + wc * 64 + n * 16 + l16;
#pragma unroll
                for (int r = 0; r < 4; ++r)
                    C[(size_t)(row + r) * NN + col] = acc[m][n][r];
            }
    } else {
#pragma unroll
        for (int m = 0; m < 4; ++m)
#pragma unroll
            for (int n = 0; n < 4; ++n) {
                int row = bi * 128 + wr * 64 + m * 16 + kh * 4;
                int col = bj * 128 + wc * 64 + n * 16 + l16;
#pragma unroll
                for (int r = 0; r < 4; ++r)
                    unsafeAtomicAdd(&C[(size_t)(row + r) * NN + col], acc[m][n][r]);
            }
    }
}

// ---------------- fp32 fallback (only if ws too small) ----------------
__global__ __launch_bounds__(256) void tri_fp32(const float* __restrict__ A,
                                                const float* __restrict__ B,
                                                float* __restrict__ C) {
    const int bi = blockIdx.y, bj = blockIdx.x, tid = threadIdx.x;
    const int r0 = (tid >> 4) << 2, c0 = (tid & 15) << 2;
    f32x4 z = {0.f, 0.f, 0.f, 0.f};
    if (bi > bj) {
#pragma unroll
        for (int r = 0; r < 4; ++r)
            *reinterpret_cast<f32x4*>(C + (size_t)(bi * 64 + r0 + r) * NN + bj * 64 + c0) = z;
        return;
    }
    __shared__ float As[64][65], Bs[64][65];
    float acc[4][4] = {};
    for (int kt = bi; kt <= bj; ++kt) {
        const int k0 = kt * 64;
#pragma unroll
        for (int q = 0; q < 4; ++q) {
            int g = q * 256 + tid, r = g >> 4, f4 = g & 15;
            f32x4 va = *reinterpret_cast<const f32x4*>(A + (size_t)(bi * 64 + r) * NN + k0 + f4 * 4);
            f32x4 vb = *reinterpret_cast<const f32x4*>(B + (size_t)(k0 + r) * NN + bj * 64 + f4 * 4);
#pragma unroll
            for (int j = 0; j < 4; ++j) {
                As[r][f4 * 4 + j] = (k0 + f4 * 4 + j >= bi * 64 + r) ? va[j] : 0.f;
                Bs[r][f4 * 4 + j] = (bj * 64 + f4 * 4 + j >= k0 + r) ? vb[j] : 0.f;
            }
        }
        __syncthreads();
        for (int kk = 0; kk < 64; ++kk) {
#pragma unroll
            for (int r = 0; r < 4; ++r) {
                float a = As[r0 + r][kk];
#pragma unroll
                for (int cc = 0; cc < 4; ++cc) acc[r][cc] += a * Bs[kk][c0 + cc];
            }
        }
        __syncthreads();
    }
#pragma unroll
    for (int r = 0; r < 4; ++r) {
        f32x4 o = {acc[r][0], acc[r][1], acc[r][2], acc[r][3]};
        *reinterpret_cast<f32x4*>(C + (size_t)(bi * 64 + r0 + r) * NN + bj * 64 + c0) = o;
    }
}

extern "C" void kernel_launch(void* const* d_in, const int* in_sizes, int n_in,
                              void* d_out, int out_size, void* d_ws, size_t ws_size,
                              hipStream_t stream) {
    const float* A = (const float*)d_in[0];
    const float* B = (const float*)d_in[1];
    float* C = (float*)d_out;

    const size_t need = (size_t)2 * NN * NN * sizeof(ushort);   // 64 MB
    if (ws_size >= need) {
        ushort* Au  = (ushort*)d_ws;
        ushort* BTu = Au + (size_t)NN * NN;
        prep<<<dim3(32, 32, 3), 256, 0, stream>>>(A, B, Au, BTu, C);
        hipError_t e = hipFuncSetAttribute((const void*)trimm_8ph,
                                           hipFuncAttributeMaxDynamicSharedMemorySize, 131072);
        if (e == hipSuccess) {
            trimm_8ph<<<NBLK, 512, 131072, stream>>>(Au, BTu, C);
        } else {
            trimm_split<<<GRID16, 256, 0, stream>>>(Au, BTu, C);
        }
    } else {
        tri_fp32<<<dim3(64, 64), 256, 0, stream>>>(A, B, C);
    }
}

// Round 23
// 108.368 us; speedup vs baseline: 1.2442x; 1.0964x over previous
//
#include <hip/hip_runtime.h>
#include <hip/hip_bf16.h>
#include <stdint.h>

#define NN 4096
#define NT 32                      // 128-wide tiles per side
#define SLOTS_PER_XCD 132          // max jobs per XCD group (x=0)
#define GRID_TOT (8 * SLOTS_PER_XCD)

typedef __attribute__((ext_vector_type(8))) __bf16 bf16x8;
typedef __attribute__((ext_vector_type(8))) short  s16x8;
typedef __attribute__((ext_vector_type(4))) float  f32x4;

__device__ __forceinline__ ushort f2bf(float f) {
    uint32_t u = __builtin_bit_cast(uint32_t, f);
    u += 0x7fffu + ((u >> 16) & 1u);            // RNE to bf16
    return (ushort)(u >> 16);
}

// jobs in column bj: sum_{m=1}^{bj+1} ceil(m/8)
__device__ __forceinline__ int col_jobs(int bj) {
    int L = bj + 1, a = L >> 3, b = L & 7;
    return 4 * a * (a + 1) + b * (a + 1);
}

// ---------- fused prep: z=0 conv A (triu, bf16), z=1 conv B^T (triu, bf16), z=2 zero C tiles ----------
__global__ __launch_bounds__(256) void prep(const float* __restrict__ A,
                                            const float* __restrict__ B,
                                            ushort* __restrict__ Au,
                                            ushort* __restrict__ BTu,
                                            float* __restrict__ C) {
    const int role = blockIdx.z;
    const int tr = blockIdx.y;
    const int tc = blockIdx.x;
    const int tid = threadIdx.x;

    if (role == 0) {
        if (tc < tr) return;                     // lower A-tiles never read
        const bool diag = (tc == tr);
#pragma unroll
        for (int q = 0; q < 8; ++q) {
            int g = q * 256 + tid;
            int r = g >> 4, c0 = (g & 15) << 3;
            int row = tr * 128 + r, col0 = tc * 128 + c0;
            const float* p = A + (size_t)row * NN + col0;
            f32x4 a0 = *reinterpret_cast<const f32x4*>(p);
            f32x4 a1 = *reinterpret_cast<const f32x4*>(p + 4);
            s16x8 o;
#pragma unroll
            for (int j = 0; j < 8; ++j) {
                float f = (j < 4) ? a0[j] : a1[j - 4];
                if (diag && (col0 + j) < row) f = 0.0f;
                o[j] = (short)f2bf(f);
            }
            *reinterpret_cast<s16x8*>(Au + (size_t)row * NN + col0) = o;
        }
        return;
    }

    if (role == 1) {
        // BTu[j][k] = (j >= k) ? bf16(B[k][j]) : 0 ; tr = k-tile, tc = j-tile
        if (tc < tr) return;
        const bool diag = (tc == tr);
        // pad 129: transpose-read row stride = 8*129 ushorts -> bank stride 4 -> 2-way (free)
        __shared__ ushort tile[128][129];
        // r23: 32B/thread reads (2 x f32x4), 8 iterations — matches role 0's width
#pragma unroll
        for (int q = 0; q < 8; ++q) {
            int g = q * 256 + tid;               // 2048 groups of 8 floats
            int r = g >> 4, c0 = (g & 15) << 3;
            int krow = tr * 128 + r;
            const float* p = B + (size_t)krow * NN + tc * 128 + c0;
            f32x4 v0 = *reinterpret_cast<const f32x4*>(p);
            f32x4 v1 = *reinterpret_cast<const f32x4*>(p + 4);
#pragma unroll
            for (int j = 0; j < 8; ++j) {
                int col = c0 + j;
                float f = (j < 4) ? v0[j] : v1[j - 4];
                if (diag && (tc * 128 + col) < krow) f = 0.0f;
                tile[r][col] = f2bf(f);
            }
        }
        __syncthreads();
#pragma unroll
        for (int q = 0; q < 8; ++q) {
            int g = q * 256 + tid;
            int orow = g >> 4, ch = g & 15;
            s16x8 o;
#pragma unroll
            for (int j = 0; j < 8; ++j) o[j] = (short)tile[ch * 8 + j][orow];
            *reinterpret_cast<s16x8*>(BTu + (size_t)(tc * 128 + orow) * NN + tr * 128 + ch * 8) = o;
        }
        return;
    }

    // role 2: zero C tile if lower-tri OR multi-chunk upper tile (d >= 8 -> atomic-accumulated)
    {
        int d = tc - tr;
        bool need = (d < 0) || (d >= 8);
        if (!need) return;
        int r = tid >> 1, cb = (tid & 1) * 64;
        float* p = C + (size_t)(tr * 128 + r) * NN + tc * 128 + cb;
        f32x4 z = {0.f, 0.f, 0.f, 0.f};
#pragma unroll
        for (int v = 0; v < 16; ++v) *reinterpret_cast<f32x4*>(p + v * 4) = z;
    }
}

// ---------------- split-K MFMA kernel (r16, session best): 128x128, BK=32, 2-deep counted-vmcnt ----------------
// Best-measured configuration (75.0us trimm / 111.55us total): XCD column grouping (r12, FETCH
// 152->95MB), counted vmcnt(4) pipeline (r14, -12%), coalescing-preserving XOR swizzle (r16,
// conflicts 3.06M->0). 11 structural variants (locality/conflicts/barriers/granularity/tile/
// sync-free/deep-pipe) all land 75-107us: concurrency-starved at this intrinsic work size
// (22.9 GFLOP), matching the documented small-N plateau of these structures (m102 curve).
__global__ __launch_bounds__(256) void trimm_split(const ushort* __restrict__ Au,
                                                   const ushort* __restrict__ BTu,
                                                   float* __restrict__ C) {
    const int tid = threadIdx.x;
    const int xcd = blockIdx.x & 7;
    int slot = blockIdx.x >> 3;

    // ---- decode (xcd, slot) -> (bi, bj, chunk c of nch) ----
    const int cols[4] = {31 - xcd, 16 + xcd, 15 - xcd, xcd};   // work-descending
    int bj = -1;
    for (int ci = 0; ci < 4; ++ci) {
        int cj = cols[ci], n = col_jobs(cj);
        if (slot < n) { bj = cj; break; }
        slot -= n;
    }
    if (bj < 0) return;                           // idle slot (grid padding)

    int bi = 0, c = 0, nch = 1;
    for (int i = 0; i <= bj; ++i) {
        int nc = (bj - i + 8) >> 3;               // ceil((bj-i+1)/8)
        if (slot < nc) { bi = i; c = slot; nch = nc; break; }
        slot -= nc;
    }
    const int d = bj - bi;
    const int L = d + 1;                          // k-tiles of 128 in [bi, bj]
    const int kt0 = (c * L) / nch, kt1 = ((c + 1) * L) / nch;
    const int k_base = (bi + kt0) * 128;
    const int nsteps = (kt1 - kt0) * 4;           // BK=32 steps (always >= 4)

    __shared__ ushort lA[2][128 * 32];            // 2 x 8 KB
    __shared__ ushort lB[2][128 * 32];            // 2 x 8 KB

    const int wid = tid >> 6, lane = tid & 63;
    const int wr = wid >> 1, wc = wid & 1;
    const int l16 = lane & 15, kh = lane >> 4;

    // staging: chunk g -> linear LDS 16B-slot g; source = (row = g>>2, kslot = (g&3)^((g>>3)&3))
    const int g0 = (wid * 2 + 0) * 64 + lane;
    const int g1 = (wid * 2 + 1) * 64 + lane;
    const int ks0 = ((g0 & 3) ^ ((g0 >> 3) & 3)) << 3;
    const int ks1 = ((g1 & 3) ^ ((g1 >> 3) & 3)) << 3;
    const ushort* gaB0 = Au  + (size_t)(bi * 128 + (g0 >> 2)) * NN + ks0 + k_base;
    const ushort* gaB1 = Au  + (size_t)(bi * 128 + (g1 >> 2)) * NN + ks1 + k_base;
    const ushort* gbB0 = BTu + (size_t)(bj * 128 + (g0 >> 2)) * NN + ks0 + k_base;
    const ushort* gbB1 = BTu + (size_t)(bj * 128 + (g1 >> 2)) * NN + ks1 + k_base;
    const int lo0 = (wid * 2 + 0) * 512;
    const int lo1 = (wid * 2 + 1) * 512;

#define STAGE(buf, off)                                                                            \
    do {                                                                                           \
        __builtin_amdgcn_global_load_lds((const __attribute__((address_space(1))) void*)(gaB0 + (off)), \
                                         (__attribute__((address_space(3))) void*)(&lA[buf][lo0]), 16, 0, 0); \
        __builtin_amdgcn_global_load_lds((const __attribute__((address_space(1))) void*)(gaB1 + (off)), \
                                         (__attribute__((address_space(3))) void*)(&lA[buf][lo1]), 16, 0, 0); \
        __builtin_amdgcn_global_load_lds((const __attribute__((address_space(1))) void*)(gbB0 + (off)), \
                                         (__attribute__((address_space(3))) void*)(&lB[buf][lo0]), 16, 0, 0); \
        __builtin_amdgcn_global_load_lds((const __attribute__((address_space(1))) void*)(gbB1 + (off)), \
                                         (__attribute__((address_space(3))) void*)(&lB[buf][lo1]), 16, 0, 0); \
    } while (0)

    f32x4 zero = {0.f, 0.f, 0.f, 0.f};
    f32x4 acc[4][4];
#pragma unroll
    for (int m = 0; m < 4; ++m)
#pragma unroll
        for (int n = 0; n < 4; ++n) acc[m][n] = zero;

    // prologue: 2 stages in flight
    STAGE(0, 0);
    if (nsteps > 1) STAGE(1, 32);

    for (int t = 0; t < nsteps; ++t) {
        const int cur = t & 1;
        // wait for stage t only: stage t+1's 4 loads stay outstanding (counted vmcnt, never 0 in-loop)
        if (t + 1 < nsteps) asm volatile("s_waitcnt vmcnt(4)" ::: "memory");
        else                asm volatile("s_waitcnt vmcnt(0)" ::: "memory");
        __builtin_amdgcn_s_barrier();
        __builtin_amdgcn_sched_barrier(0);   // pin ds_reads below the barrier (cross-wave staging)

        bf16x8 af[4], bfr[4];
#pragma unroll
        for (int m = 0; m < 4; ++m) {
            int row = wr * 64 + m * 16 + l16;
            af[m] = *reinterpret_cast<const bf16x8*>(&lA[cur][row * 32 + ((kh ^ ((row >> 1) & 3)) << 3)]);
        }
#pragma unroll
        for (int n = 0; n < 4; ++n) {
            int row = wc * 64 + n * 16 + l16;
            bfr[n] = *reinterpret_cast<const bf16x8*>(&lB[cur][row * 32 + ((kh ^ ((row >> 1) & 3)) << 3)]);
        }

#pragma unroll
        for (int m = 0; m < 4; ++m)
#pragma unroll
            for (int n = 0; n < 4; ++n)
                acc[m][n] = __builtin_amdgcn_mfma_f32_16x16x32_bf16(af[m], bfr[n], acc[m][n], 0, 0, 0);

        __builtin_amdgcn_s_barrier();        // all waves done reading buf[cur]
        __builtin_amdgcn_sched_barrier(0);   // pin the overwrite below the barrier
        if (t + 2 < nsteps) STAGE(cur, (t + 2) * 32);
    }
#undef STAGE

    // C/D layout: col = lane&15, row = (lane>>4)*4 + reg
    if (nch == 1) {
#pragma unroll
        for (int m = 0; m < 4; ++m)
#pragma unroll
            for (int n = 0; n < 4; ++n) {
                int row = bi * 128 + wr * 64 + m * 16 + kh * 4;
                int col = bj * 128 + wc * 64 + n * 16 + l16;
#pragma unroll
                for (int r = 0; r < 4; ++r)
                    C[(size_t)(row + r) * NN + col] = acc[m][n][r];
            }
    } else {
#pragma unroll
        for (int m = 0; m < 4; ++m)
#pragma unroll
            for (int n = 0; n < 4; ++n) {
                int row = bi * 128 + wr * 64 + m * 16 + kh * 4;
                int col = bj * 128 + wc * 64 + n * 16 + l16;
#pragma unroll
                for (int r = 0; r < 4; ++r)
                    unsafeAtomicAdd(&C[(size_t)(row + r) * NN + col], acc[m][n][r]);
            }
    }
}

// ---------------- fp32 fallback (only if ws too small) ----------------
__global__ __launch_bounds__(256) void tri_fp32(const float* __restrict__ A,
                                                const float* __restrict__ B,
                                                float* __restrict__ C) {
    const int bi = blockIdx.y, bj = blockIdx.x, tid = threadIdx.x;
    const int r0 = (tid >> 4) << 2, c0 = (tid & 15) << 2;
    f32x4 z = {0.f, 0.f, 0.f, 0.f};
    if (bi > bj) {
#pragma unroll
        for (int r = 0; r < 4; ++r)
            *reinterpret_cast<f32x4*>(C + (size_t)(bi * 64 + r0 + r) * NN + bj * 64 + c0) = z;
        return;
    }
    __shared__ float As[64][65], Bs[64][65];
    float acc[4][4] = {};
    for (int kt = bi; kt <= bj; ++kt) {
        const int k0 = kt * 64;
#pragma unroll
        for (int q = 0; q < 4; ++q) {
            int g = q * 256 + tid, r = g >> 4, f4 = g & 15;
            f32x4 va = *reinterpret_cast<const f32x4*>(A + (size_t)(bi * 64 + r) * NN + k0 + f4 * 4);
            f32x4 vb = *reinterpret_cast<const f32x4*>(B + (size_t)(k0 + r) * NN + bj * 64 + f4 * 4);
#pragma unroll
            for (int j = 0; j < 4; ++j) {
                As[r][f4 * 4 + j] = (k0 + f4 * 4 + j >= bi * 64 + r) ? va[j] : 0.f;
                Bs[r][f4 * 4 + j] = (bj * 64 + f4 * 4 + j >= k0 + r) ? vb[j] : 0.f;
            }
        }
        __syncthreads();
        for (int kk = 0; kk < 64; ++kk) {
#pragma unroll
            for (int r = 0; r < 4; ++r) {
                float a = As[r0 + r][kk];
#pragma unroll
                for (int cc = 0; cc < 4; ++cc) acc[r][cc] += a * Bs[kk][c0 + cc];
            }
        }
        __syncthreads();
    }
#pragma unroll
    for (int r = 0; r < 4; ++r) {
        f32x4 o = {acc[r][0], acc[r][1], acc[r][2], acc[r][3]};
        *reinterpret_cast<f32x4*>(C + (size_t)(bi * 64 + r0 + r) * NN + bj * 64 + c0) = o;
    }
}

extern "C" void kernel_launch(void* const* d_in, const int* in_sizes, int n_in,
                              void* d_out, int out_size, void* d_ws, size_t ws_size,
                              hipStream_t stream) {
    const float* A = (const float*)d_in[0];
    const float* B = (const float*)d_in[1];
    float* C = (float*)d_out;

    const size_t need = (size_t)2 * NN * NN * sizeof(ushort);   // 64 MB
    if (ws_size >= need) {
        ushort* Au  = (ushort*)d_ws;
        ushort* BTu = Au + (size_t)NN * NN;
        prep<<<dim3(32, 32, 3), 256, 0, stream>>>(A, B, Au, BTu, C);
        trimm_split<<<GRID_TOT, 256, 0, stream>>>(Au, BTu, C);
    } else {
        tri_fp32<<<dim3(64, 64), 256, 0, stream>>>(A, B, C);
    }
}

// Round 24
// 101.561 us; speedup vs baseline: 1.3276x; 1.0670x over previous
//
#include <hip/hip_runtime.h>
#include <hip/hip_bf16.h>
#include <stdint.h>

#define NN 4096
#define NT 32                      // 128-wide tiles per side
#define SLOTS_PER_XCD 132          // max jobs per XCD group (x=0)
#define GRID_TOT (8 * SLOTS_PER_XCD)

typedef __attribute__((ext_vector_type(8))) __bf16 bf16x8;
typedef __attribute__((ext_vector_type(8))) short  s16x8;
typedef __attribute__((ext_vector_type(4))) float  f32x4;

__device__ __forceinline__ ushort f2bf(float f) {
    uint32_t u = __builtin_bit_cast(uint32_t, f);
    u += 0x7fffu + ((u >> 16) & 1u);            // RNE to bf16
    return (ushort)(u >> 16);
}

// jobs in column bj: sum_{m=1}^{bj+1} ceil(m/8)
__device__ __forceinline__ int col_jobs(int bj) {
    int L = bj + 1, a = L >> 3, b = L & 7;
    return 4 * a * (a + 1) + b * (a + 1);
}

// ---------- fused prep: z=0 conv A (triu, bf16), z=1 conv B^T (triu, bf16), z=2 zero C tiles ----------
__global__ __launch_bounds__(256) void prep(const float* __restrict__ A,
                                            const float* __restrict__ B,
                                            ushort* __restrict__ Au,
                                            ushort* __restrict__ BTu,
                                            float* __restrict__ C) {
    const int role = blockIdx.z;
    const int tr = blockIdx.y;
    const int tc = blockIdx.x;
    const int tid = threadIdx.x;

    if (role == 0) {
        if (tc < tr) return;                     // lower A-tiles never read
        const bool diag = (tc == tr);
#pragma unroll
        for (int q = 0; q < 8; ++q) {
            int g = q * 256 + tid;
            int r = g >> 4, c0 = (g & 15) << 3;
            int row = tr * 128 + r, col0 = tc * 128 + c0;
            const float* p = A + (size_t)row * NN + col0;
            f32x4 a0 = *reinterpret_cast<const f32x4*>(p);
            f32x4 a1 = *reinterpret_cast<const f32x4*>(p + 4);
            s16x8 o;
#pragma unroll
            for (int j = 0; j < 8; ++j) {
                float f = (j < 4) ? a0[j] : a1[j - 4];
                if (diag && (col0 + j) < row) f = 0.0f;
                o[j] = (short)f2bf(f);
            }
            *reinterpret_cast<s16x8*>(Au + (size_t)row * NN + col0) = o;
        }
        return;
    }

    if (role == 1) {
        // BTu[j][k] = (j >= k) ? bf16(B[k][j]) : 0 ; tr = k-tile, tc = j-tile
        if (tc < tr) return;
        const bool diag = (tc == tr);
        __shared__ ushort tile[128][129];        // pad 129: transpose read 2-way (free)
#pragma unroll
        for (int q = 0; q < 8; ++q) {
            int g = q * 256 + tid;               // 2048 groups of 8 floats (32B/thread, r23)
            int r = g >> 4, c0 = (g & 15) << 3;
            int krow = tr * 128 + r;
            const float* p = B + (size_t)krow * NN + tc * 128 + c0;
            f32x4 v0 = *reinterpret_cast<const f32x4*>(p);
            f32x4 v1 = *reinterpret_cast<const f32x4*>(p + 4);
#pragma unroll
            for (int j = 0; j < 8; ++j) {
                int col = c0 + j;
                float f = (j < 4) ? v0[j] : v1[j - 4];
                if (diag && (tc * 128 + col) < krow) f = 0.0f;
                tile[r][col] = f2bf(f);
            }
        }
        __syncthreads();
#pragma unroll
        for (int q = 0; q < 8; ++q) {
            int g = q * 256 + tid;
            int orow = g >> 4, ch = g & 15;
            s16x8 o;
#pragma unroll
            for (int j = 0; j < 8; ++j) o[j] = (short)tile[ch * 8 + j][orow];
            *reinterpret_cast<s16x8*>(BTu + (size_t)(tc * 128 + orow) * NN + tr * 128 + ch * 8) = o;
        }
        return;
    }

    // role 2: zero C tile if lower-tri OR multi-chunk upper tile (d >= 8 -> atomic-accumulated)
    {
        int d = tc - tr;
        bool need = (d < 0) || (d >= 8);
        if (!need) return;
        int r = tid >> 1, cb = (tid & 1) * 64;
        float* p = C + (size_t)(tr * 128 + r) * NN + tc * 128 + cb;
        f32x4 z = {0.f, 0.f, 0.f, 0.f};
#pragma unroll
        for (int v = 0; v < 16; ++v) *reinterpret_cast<f32x4*>(p + v * 4) = z;
    }
}

// ---------------- split-K MFMA kernel: 128x128, BK=64, 2-deep counted-vmcnt pipeline ----------------
// r24: BK 32->64 on the r16/r23 structure. Per-step model (r14-r22): ~3700cy/block-step, real work
// ~1500cy -> the barrier rendezvous+wait is paid per step. BK=64 halves steps/barriers per k-tile
// at same block count/atomics (r18's finer-split failed by ADDING per-block costs; this removes
// per-step costs). LDS 64KB (2 ops x 2 bufs x 128x64) -> 2 blocks/CU = current effective occupancy.
// Swizzle for 128B row stride: chunk g -> row=g>>3, slot s=g&7 sources kslot s^(row&7); read kslot
// k'=h*4+kh at slot k'^(row&7): 64 lanes -> 8 lanes/4-bank group = uniform = LDS minimum.
__global__ __launch_bounds__(256) void trimm_split(const ushort* __restrict__ Au,
                                                   const ushort* __restrict__ BTu,
                                                   float* __restrict__ C) {
    const int tid = threadIdx.x;
    const int xcd = blockIdx.x & 7;
    int slot = blockIdx.x >> 3;

    // ---- decode (xcd, slot) -> (bi, bj, chunk c of nch) ----
    const int cols[4] = {31 - xcd, 16 + xcd, 15 - xcd, xcd};   // work-descending
    int bj = -1;
    for (int ci = 0; ci < 4; ++ci) {
        int cj = cols[ci], n = col_jobs(cj);
        if (slot < n) { bj = cj; break; }
        slot -= n;
    }
    if (bj < 0) return;                           // idle slot (grid padding)

    int bi = 0, c = 0, nch = 1;
    for (int i = 0; i <= bj; ++i) {
        int nc = (bj - i + 8) >> 3;               // ceil((bj-i+1)/8)
        if (slot < nc) { bi = i; c = slot; nch = nc; break; }
        slot -= nc;
    }
    const int d = bj - bi;
    const int L = d + 1;                          // k-tiles of 128 in [bi, bj]
    const int kt0 = (c * L) / nch, kt1 = ((c + 1) * L) / nch;
    const int k_base = (bi + kt0) * 128;
    const int nsteps = (kt1 - kt0) * 2;           // BK=64 steps (always >= 2)

    __shared__ ushort lA[2][128 * 64];            // 2 x 16 KB
    __shared__ ushort lB[2][128 * 64];            // 2 x 16 KB  (64 KB total -> 2 blocks/CU)

    const int wid = tid >> 6, lane = tid & 63;
    const int wr = wid >> 1, wc = wid & 1;
    const int l16 = lane & 15, kh = lane >> 4;

    // staging: 1024 chunks/operand/stage; thread does g = q*256+tid, q=0..3, per operand.
    // chunk g -> LDS ushort offset g*8 (row=g>>3, slot=g&7); source kslot = (g&7)^((g>>3)&7)
    const int gq0 = 0 * 256 + tid, gq1 = 1 * 256 + tid, gq2 = 2 * 256 + tid, gq3 = 3 * 256 + tid;
#define KS(g) (((((g) & 7) ^ (((g) >> 3) & 7))) << 3)
#define RW(g) ((g) >> 3)
    const ushort* pA0 = Au  + (size_t)(bi * 128 + RW(gq0)) * NN + KS(gq0) + k_base;
    const ushort* pA1 = Au  + (size_t)(bi * 128 + RW(gq1)) * NN + KS(gq1) + k_base;
    const ushort* pA2 = Au  + (size_t)(bi * 128 + RW(gq2)) * NN + KS(gq2) + k_base;
    const ushort* pA3 = Au  + (size_t)(bi * 128 + RW(gq3)) * NN + KS(gq3) + k_base;
    const ushort* pB0 = BTu + (size_t)(bj * 128 + RW(gq0)) * NN + KS(gq0) + k_base;
    const ushort* pB1 = BTu + (size_t)(bj * 128 + RW(gq1)) * NN + KS(gq1) + k_base;
    const ushort* pB2 = BTu + (size_t)(bj * 128 + RW(gq2)) * NN + KS(gq2) + k_base;
    const ushort* pB3 = BTu + (size_t)(bj * 128 + RW(gq3)) * NN + KS(gq3) + k_base;
#undef KS
#undef RW
    const int lo0 = gq0 * 8, lo1 = gq1 * 8, lo2 = gq2 * 8, lo3 = gq3 * 8;

#define GLOAD(src, dst) __builtin_amdgcn_global_load_lds(                      \
        (const __attribute__((address_space(1))) void*)(src),                  \
        (__attribute__((address_space(3))) void*)(dst), 16, 0, 0)
#define STAGE(buf, off)                                                        \
    do {                                                                       \
        GLOAD(pA0 + (off), &lA[buf][lo0]); GLOAD(pA1 + (off), &lA[buf][lo1]);  \
        GLOAD(pA2 + (off), &lA[buf][lo2]); GLOAD(pA3 + (off), &lA[buf][lo3]);  \
        GLOAD(pB0 + (off), &lB[buf][lo0]); GLOAD(pB1 + (off), &lB[buf][lo1]);  \
        GLOAD(pB2 + (off), &lB[buf][lo2]); GLOAD(pB3 + (off), &lB[buf][lo3]);  \
    } while (0)

    f32x4 zero = {0.f, 0.f, 0.f, 0.f};
    f32x4 acc[4][4];
#pragma unroll
    for (int m = 0; m < 4; ++m)
#pragma unroll
        for (int n = 0; n < 4; ++n) acc[m][n] = zero;

    // prologue: 2 stages in flight (8 loads each)
    STAGE(0, 0);
    if (nsteps > 1) STAGE(1, 64);

    for (int t = 0; t < nsteps; ++t) {
        const int cur = t & 1;
        // wait for stage t only: stage t+1's 8 loads stay outstanding (counted vmcnt, never 0 in-loop)
        if (t + 1 < nsteps) asm volatile("s_waitcnt vmcnt(8)" ::: "memory");
        else                asm volatile("s_waitcnt vmcnt(0)" ::: "memory");
        __builtin_amdgcn_s_barrier();
        __builtin_amdgcn_sched_barrier(0);   // pin ds_reads below the barrier (cross-wave staging)

        // two K=32 halves from the same buffer (no barrier between: read-only)
#pragma unroll
        for (int h = 0; h < 2; ++h) {
            bf16x8 af[4], bfr[4];
#pragma unroll
            for (int m = 0; m < 4; ++m) {
                int row = wr * 64 + m * 16 + l16;
                af[m] = *reinterpret_cast<const bf16x8*>(
                    &lA[cur][row * 64 + (((h * 4 + kh) ^ (row & 7)) << 3)]);
            }
#pragma unroll
            for (int n = 0; n < 4; ++n) {
                int row = wc * 64 + n * 16 + l16;
                bfr[n] = *reinterpret_cast<const bf16x8*>(
                    &lB[cur][row * 64 + (((h * 4 + kh) ^ (row & 7)) << 3)]);
            }
#pragma unroll
            for (int m = 0; m < 4; ++m)
#pragma unroll
                for (int n = 0; n < 4; ++n)
                    acc[m][n] = __builtin_amdgcn_mfma_f32_16x16x32_bf16(af[m], bfr[n], acc[m][n], 0, 0, 0);
        }

        __builtin_amdgcn_s_barrier();        // all waves done reading buf[cur]
        __builtin_amdgcn_sched_barrier(0);   // pin the overwrite below the barrier
        if (t + 2 < nsteps) STAGE(cur, (t + 2) * 64);
    }
#undef STAGE
#undef GLOAD

    // C/D layout: col = lane&15, row = (lane>>4)*4 + reg
    if (nch == 1) {
#pragma unroll
        for (int m = 0; m < 4; ++m)
#pragma unroll
            for (int n = 0; n < 4; ++n) {
                int row = bi * 128 + wr * 64 + m * 16 + kh * 4;
                int col = bj * 128 + wc * 64 + n * 16 + l16;
#pragma unroll
                for (int r = 0; r < 4; ++r)
                    C[(size_t)(row + r) * NN + col] = acc[m][n][r];
            }
    } else {
#pragma unroll
        for (int m = 0; m < 4; ++m)
#pragma unroll
            for (int n = 0; n < 4; ++n) {
                int row = bi * 128 + wr * 64 + m * 16 + kh * 4;
                int col = bj * 128 + wc * 64 + n * 16 + l16;
#pragma unroll
                for (int r = 0; r < 4; ++r)
                    unsafeAtomicAdd(&C[(size_t)(row + r) * NN + col], acc[m][n][r]);
            }
    }
}

// ---------------- fp32 fallback (only if ws too small) ----------------
__global__ __launch_bounds__(256) void tri_fp32(const float* __restrict__ A,
                                                const float* __restrict__ B,
                                                float* __restrict__ C) {
    const int bi = blockIdx.y, bj = blockIdx.x, tid = threadIdx.x;
    const int r0 = (tid >> 4) << 2, c0 = (tid & 15) << 2;
    f32x4 z = {0.f, 0.f, 0.f, 0.f};
    if (bi > bj) {
#pragma unroll
        for (int r = 0; r < 4; ++r)
            *reinterpret_cast<f32x4*>(C + (size_t)(bi * 64 + r0 + r) * NN + bj * 64 + c0) = z;
        return;
    }
    __shared__ float As[64][65], Bs[64][65];
    float acc[4][4] = {};
    for (int kt = bi; kt <= bj; ++kt) {
        const int k0 = kt * 64;
#pragma unroll
        for (int q = 0; q < 4; ++q) {
            int g = q * 256 + tid, r = g >> 4, f4 = g & 15;
            f32x4 va = *reinterpret_cast<const f32x4*>(A + (size_t)(bi * 64 + r) * NN + k0 + f4 * 4);
            f32x4 vb = *reinterpret_cast<const f32x4*>(B + (size_t)(k0 + r) * NN + bj * 64 + f4 * 4);
#pragma unroll
            for (int j = 0; j < 4; ++j) {
                As[r][f4 * 4 + j] = (k0 + f4 * 4 + j >= bi * 64 + r) ? va[j] : 0.f;
                Bs[r][f4 * 4 + j] = (bj * 64 + f4 * 4 + j >= k0 + r) ? vb[j] : 0.f;
            }
        }
        __syncthreads();
        for (int kk = 0; kk < 64; ++kk) {
#pragma unroll
            for (int r = 0; r < 4; ++r) {
                float a = As[r0 + r][kk];
#pragma unroll
                for (int cc = 0; cc < 4; ++cc) acc[r][cc] += a * Bs[kk][c0 + cc];
            }
        }
        __syncthreads();
    }
#pragma unroll
    for (int r = 0; r < 4; ++r) {
        f32x4 o = {acc[r][0], acc[r][1], acc[r][2], acc[r][3]};
        *reinterpret_cast<f32x4*>(C + (size_t)(bi * 64 + r0 + r) * NN + bj * 64 + c0) = o;
    }
}

extern "C" void kernel_launch(void* const* d_in, const int* in_sizes, int n_in,
                              void* d_out, int out_size, void* d_ws, size_t ws_size,
                              hipStream_t stream) {
    const float* A = (const float*)d_in[0];
    const float* B = (const float*)d_in[1];
    float* C = (float*)d_out;

    const size_t need = (size_t)2 * NN * NN * sizeof(ushort);   // 64 MB
    if (ws_size >= need) {
        ushort* Au  = (ushort*)d_ws;
        ushort* BTu = Au + (size_t)NN * NN;
        prep<<<dim3(32, 32, 3), 256, 0, stream>>>(A, B, Au, BTu, C);
        trimm_split<<<GRID_TOT, 256, 0, stream>>>(Au, BTu, C);
    } else {
        tri_fp32<<<dim3(64, 64), 256, 0, stream>>>(A, B, C);
    }
}